// Round 1
// baseline (3353.505 us; speedup 1.0000x reference)
//
#include <hip/hip_runtime.h>
#include <math.h>

// Problem constants: B=4096 batches, R=130 ROIs, T=200, Q=64.
// Pipeline (BN = training-mode batch stats over (0,2), folded to affine a*x+c):
//   k_in   : clean NaN, qk = x@wq.T + bq (B,130,64); xw1 = x@w1.T (B,130,16)
//   k_rel  : rel = Qm@Km (reshape trick) (B,130,130) + per-(r,b) partial stats
//   k_stats: reduce partials -> a[r], c[r] for a BN stage
//   k_A    : in-place affine+softmax+relu(x-thr) on rel; fused GCN1: Z1 = A@xw1 + b1 (+stats)
//   k_gcn  : h = relu(aP*ZP+cP) [+ relu(aQ*ZQ+cQ)]; g = h@W.T; Z = A@g + b (+stats)
//   k_mlp  : h6 -> (B,260) @ w_mlp.T + b_mlp, relu -> out (B,2)

__global__ __launch_bounds__(256) void k_in(
    const float* __restrict__ x, const float* __restrict__ wq,
    const float* __restrict__ bq, const float* __restrict__ w1,
    float* __restrict__ qk, float* __restrict__ xw1)
{
  __shared__ float xs[64 * 204];              // 64 rows x 200, stride 204 (16B-aligned, conflict-free)
  const int tid = threadIdx.x;
  const size_t m0 = (size_t)blockIdx.x * 64;  // 8320 blocks * 64 rows = 532480 = B*R
  const float4* xsrc = (const float4*)(x + m0 * 200);
  for (int i = tid; i < 3200; i += 256) {
    int r = i / 50, c = i - r * 50;
    float4 v = xsrc[i];
    v.x = (v.x != v.x) ? 0.f : v.x;
    v.y = (v.y != v.y) ? 0.f : v.y;
    v.z = (v.z != v.z) ? 0.f : v.z;
    v.w = (v.w != v.w) ? 0.f : v.w;
    *((float4*)&xs[r * 204 + c * 4]) = v;
  }
  __syncthreads();
  const int fg = tid & 15, mg = tid >> 4;     // 16 feature groups x 5 feats, 16 row groups x 4 rows
  const float* wp[5];
#pragma unroll
  for (int j = 0; j < 5; j++) {
    int f = fg * 5 + j;                       // f<64 -> wq row f; else w1 row f-64
    wp[j] = (f < 64) ? (wq + f * 200) : (w1 + (f - 64) * 200);
  }
  float acc[4][5];
#pragma unroll
  for (int i = 0; i < 4; i++)
#pragma unroll
    for (int j = 0; j < 5; j++) acc[i][j] = 0.f;
  for (int t = 0; t < 200; t += 4) {
    float4 xv[4], wv[5];
#pragma unroll
    for (int i = 0; i < 4; i++) xv[i] = *((const float4*)&xs[(mg * 4 + i) * 204 + t]);
#pragma unroll
    for (int j = 0; j < 5; j++) wv[j] = *((const float4*)(wp[j] + t));
#pragma unroll
    for (int i = 0; i < 4; i++)
#pragma unroll
      for (int j = 0; j < 5; j++)
        acc[i][j] += xv[i].x * wv[j].x + xv[i].y * wv[j].y + xv[i].z * wv[j].z + xv[i].w * wv[j].w;
  }
  __syncthreads();
  float* outt = xs;                           // reuse LDS as out[64][81]
#pragma unroll
  for (int i = 0; i < 4; i++)
#pragma unroll
    for (int j = 0; j < 5; j++)
      outt[(mg * 4 + i) * 81 + fg * 5 + j] = acc[i][j];
  __syncthreads();
  for (int i = tid; i < 4096; i += 256) {     // coalesced qk write (+bq)
    int r = i >> 6, c = i & 63;
    qk[(m0 + r) * 64 + c] = outt[r * 81 + c] + bq[c];
  }
  for (int i = tid; i < 1024; i += 256) {     // xw1 WITHOUT bias (added after A-matmul)
    int r = i >> 4, c = i & 15;
    xw1[(m0 + r) * 16 + c] = outt[r * 81 + 64 + c];
  }
}

__global__ __launch_bounds__(256) void k_rel(
    const float* __restrict__ qk, float* __restrict__ rel, float* __restrict__ sp)
{
  __shared__ float qf[8320];                  // per-batch qk, flat (130x64)
  const int b = blockIdx.x, tid = threadIdx.x;
  const float4* src = (const float4*)(qk + (size_t)b * 8320);
  float4* dst = (float4*)qf;
  for (int i = tid; i < 2080; i += 256) dst[i] = src[i];
  __syncthreads();
  const int tx = tid & 15, ty = tid >> 4;
  float acc[9][9];
#pragma unroll
  for (int i = 0; i < 9; i++)
#pragma unroll
    for (int j = 0; j < 9; j++) acc[i][j] = 0.f;
  for (int q = 0; q < 64; q++) {
    float av[9], bv[9];
#pragma unroll
    for (int i = 0; i < 9; i++) { int r = ty + 16 * i; if (r > 129) r = 129; av[i] = qf[r * 64 + q]; }
#pragma unroll
    for (int j = 0; j < 9; j++) { int s = tx + 16 * j; if (s > 129) s = 129; bv[j] = qf[q * 130 + s]; }
#pragma unroll
    for (int i = 0; i < 9; i++)
#pragma unroll
      for (int j = 0; j < 9; j++) acc[i][j] += av[i] * bv[j];   // rel[r,s]=sum_q Qm[r,q]*flat[q*130+s]
  }
  float* relb = rel + (size_t)b * 16900;
#pragma unroll
  for (int i = 0; i < 9; i++) {
    int r = ty + 16 * i;
    if (r < 130) {                            // r uniform within each 16-lane tx-group -> shuffles safe
      float s1 = 0.f, s2 = 0.f;
#pragma unroll
      for (int j = 0; j < 9; j++) {
        int s = tx + 16 * j;
        if (s < 130) {
          float v = acc[i][j];
          relb[r * 130 + s] = v;
          s1 += v; s2 += v * v;
        }
      }
#pragma unroll
      for (int m = 1; m <= 8; m <<= 1) { s1 += __shfl_xor(s1, m); s2 += __shfl_xor(s2, m); }
      if (tx == 0) { sp[(size_t)r * 4096 + b] = s1; sp[130 * 4096 + (size_t)r * 4096 + b] = s2; }
    }
  }
}

__global__ __launch_bounds__(256) void k_stats(
    const float* __restrict__ sp, const float* __restrict__ g,
    const float* __restrict__ beta, float invN, float* __restrict__ ac)
{
  const int r = blockIdx.x, tid = threadIdx.x;   // 130 blocks
  float s1 = 0.f, s2 = 0.f;
  const float* p1 = sp + (size_t)r * 4096;
  const float* p2 = sp + 130 * 4096 + (size_t)r * 4096;
  for (int j = tid; j < 4096; j += 256) { s1 += p1[j]; s2 += p2[j]; }
#pragma unroll
  for (int m = 1; m <= 32; m <<= 1) { s1 += __shfl_xor(s1, m); s2 += __shfl_xor(s2, m); }
  __shared__ float r1[4], r2[4];
  if ((tid & 63) == 0) { r1[tid >> 6] = s1; r2[tid >> 6] = s2; }
  __syncthreads();
  if (tid == 0) {
    float S1 = r1[0] + r1[1] + r1[2] + r1[3];
    float S2 = r2[0] + r2[1] + r2[2] + r2[3];
    float mean = S1 * invN;
    float var = S2 * invN - mean * mean;      // biased var
    float a = g[r] * rsqrtf(var + 1e-5f);
    ac[r] = a;
    ac[130 + r] = beta[r] - mean * a;
  }
}

__global__ __launch_bounds__(256) void k_A(
    float* __restrict__ rel, const float* __restrict__ xw1,
    const float* __restrict__ ac0, const float* __restrict__ b1,
    const float* __restrict__ thrp, float* __restrict__ Z1, float* __restrict__ sp)
{
  __shared__ float xw[2080];
  const int b = blockIdx.x, tid = threadIdx.x;
  {
    const float4* s4 = (const float4*)(xw1 + (size_t)b * 2080);
    float4* d4 = (float4*)xw;
    for (int i = tid; i < 520; i += 256) d4[i] = s4[i];
  }
  const float thr = *thrp;
  const int lane = tid & 63, wv = tid >> 6;
  float* relb = rel + (size_t)b * 16900;
  for (int r = wv; r < 130; r += 4) {         // one wave per row; 130 = 64+64+2 lanes
    const float a = ac0[r], c = ac0[130 + r];
    float v0 = a * relb[r * 130 + lane] + c;
    float v1 = a * relb[r * 130 + 64 + lane] + c;
    float v2 = (lane < 2) ? (a * relb[r * 130 + 128 + lane] + c) : -3.0e38f;
    float mx = fmaxf(v0, fmaxf(v1, v2));
#pragma unroll
    for (int m = 1; m <= 32; m <<= 1) mx = fmaxf(mx, __shfl_xor(mx, m));
    float e0 = __expf(v0 - mx), e1 = __expf(v1 - mx);
    float e2 = (lane < 2) ? __expf(v2 - mx) : 0.f;
    float s = e0 + e1 + e2;
#pragma unroll
    for (int m = 1; m <= 32; m <<= 1) s += __shfl_xor(s, m);
    float inv = 1.f / s;
    relb[r * 130 + lane] = fmaxf(e0 * inv - thr, 0.f);          // A in place of rel
    relb[r * 130 + 64 + lane] = fmaxf(e1 * inv - thr, 0.f);
    if (lane < 2) relb[r * 130 + 128 + lane] = fmaxf(e2 * inv - thr, 0.f);
  }
  __threadfence_block();
  __syncthreads();
  // fused GCN1: Z1 = A @ xw1 + b1 ; A re-read from global (L1/L2-hot)
  const int k = tid & 15, rg = tid >> 4;
  const float bk = b1[k];
  for (int rr = rg; rr < 130; rr += 16) {
    float accv = bk;
    for (int s2i = 0; s2i < 130; s2i++)
      accv += relb[rr * 130 + s2i] * xw[s2i * 16 + k];
    Z1[(size_t)b * 2080 + rr * 16 + k] = accv;
    float s1 = accv, sq = accv * accv;
#pragma unroll
    for (int m = 1; m <= 8; m <<= 1) { s1 += __shfl_xor(s1, m); sq += __shfl_xor(sq, m); }
    if (k == 0) { sp[(size_t)rr * 4096 + b] = s1; sp[130 * 4096 + (size_t)rr * 4096 + b] = sq; }
  }
}

template <int FI, int FO, bool RES>
__global__ __launch_bounds__(256) void k_gcn(
    const float* __restrict__ A, const float* __restrict__ ZP, const float* __restrict__ ZQ,
    const float* __restrict__ acP, const float* __restrict__ acQ,
    const float* __restrict__ w, const float* __restrict__ bb,
    float* __restrict__ Zout, float* __restrict__ sp)
{
  __shared__ float gs[130 * FO];
  const int b = blockIdx.x, tid = threadIdx.x;
  if (tid < 130) {
    const int r = tid;
    float h[FI];
    const float* zp = ZP + ((size_t)b * 130 + r) * FI;
    const float aP = acP[r], cP = acP[130 + r];
#pragma unroll
    for (int i = 0; i < FI; i++) h[i] = fmaxf(aP * zp[i] + cP, 0.f);
    if constexpr (RES) {
      const float* zq = ZQ + ((size_t)b * 130 + r) * FI;
      const float aQ = acQ[r], cQ = acQ[130 + r];
#pragma unroll
      for (int i = 0; i < FI; i++) h[i] += fmaxf(aQ * zq[i] + cQ, 0.f);
    }
#pragma unroll
    for (int k2 = 0; k2 < FO; k2++) {
      float s = 0.f;
#pragma unroll
      for (int i = 0; i < FI; i++) s += h[i] * w[k2 * FI + i];
      gs[r * FO + k2] = s;                    // g = h @ W.T (no bias here!)
    }
  }
  __syncthreads();
  constexpr int RP = 256 / FO;
  const int k = tid & (FO - 1), rg = tid / FO;
  const float bk = bb[k];
  const float* Ab = A + (size_t)b * 16900;
  for (int rr = rg; rr < 130; rr += RP) {
    float accv = bk;
#pragma unroll 2
    for (int s = 0; s < 130; s++) accv += Ab[rr * 130 + s] * gs[s * FO + k];
    Zout[((size_t)b * 130 + rr) * FO + k] = accv;
    float s1 = accv, s2 = accv * accv;
#pragma unroll
    for (int m = 1; m < FO; m <<= 1) { s1 += __shfl_xor(s1, m); s2 += __shfl_xor(s2, m); }
    if (k == 0) { sp[(size_t)rr * 4096 + b] = s1; sp[130 * 4096 + (size_t)rr * 4096 + b] = s2; }
  }
}

__global__ __launch_bounds__(256) void k_mlp(
    const float* __restrict__ Z5, const float* __restrict__ Z6,
    const float* __restrict__ ac5, const float* __restrict__ ac6,
    const float* __restrict__ wm, const float* __restrict__ bm, float* __restrict__ out)
{
  const int tid = threadIdx.x, lane = tid & 63, wv = tid >> 6;
  const int b = blockIdx.x * 4 + wv;          // 1024 blocks * 4 waves = 4096
  const float* z5 = Z5 + (size_t)b * 260;
  const float* z6 = Z6 + (size_t)b * 260;
  float p0 = 0.f, p1 = 0.f;
#pragma unroll
  for (int j = 0; j < 5; j++) {
    int i = lane + 64 * j;
    if (i < 260) {
      int r = i >> 1;                         // flat (130,2): channel = i/2
      float h = fmaxf(ac6[r] * z6[i] + ac6[130 + r], 0.f)
              + fmaxf(ac5[r] * z5[i] + ac5[130 + r], 0.f);
      p0 += h * wm[i];
      p1 += h * wm[260 + i];
    }
  }
#pragma unroll
  for (int m = 1; m <= 32; m <<= 1) { p0 += __shfl_xor(p0, m); p1 += __shfl_xor(p1, m); }
  if (lane == 0) {
    out[(size_t)b * 2] = fmaxf(p0 + bm[0], 0.f);
    out[(size_t)b * 2 + 1] = fmaxf(p1 + bm[1], 0.f);
  }
}

extern "C" void kernel_launch(void* const* d_in, const int* in_sizes, int n_in,
                              void* d_out, int out_size, void* d_ws, size_t ws_size,
                              hipStream_t stream) {
  const float* X   = (const float*)d_in[0];
  const float* THR = (const float*)d_in[1];
  const float* WQ  = (const float*)d_in[2];
  const float* BQ  = (const float*)d_in[3];
  const float* GT  = (const float*)d_in[4];
  const float* BT  = (const float*)d_in[5];
  const float* W1 = (const float*)d_in[6];  const float* Bb1 = (const float*)d_in[7];
  const float* G1 = (const float*)d_in[8];  const float* BE1 = (const float*)d_in[9];
  const float* W2 = (const float*)d_in[10]; const float* Bb2 = (const float*)d_in[11];
  const float* G2 = (const float*)d_in[12]; const float* BE2 = (const float*)d_in[13];
  const float* W3 = (const float*)d_in[14]; const float* Bb3 = (const float*)d_in[15];
  const float* G3 = (const float*)d_in[16]; const float* BE3 = (const float*)d_in[17];
  const float* W4 = (const float*)d_in[18]; const float* Bb4 = (const float*)d_in[19];
  const float* G4 = (const float*)d_in[20]; const float* BE4 = (const float*)d_in[21];
  const float* W5 = (const float*)d_in[22]; const float* Bb5 = (const float*)d_in[23];
  const float* G5 = (const float*)d_in[24]; const float* BE5 = (const float*)d_in[25];
  const float* W6 = (const float*)d_in[26]; const float* Bb6 = (const float*)d_in[27];
  const float* G6 = (const float*)d_in[28]; const float* BE6 = (const float*)d_in[29];
  const float* WM = (const float*)d_in[30]; const float* BM = (const float*)d_in[31];

  float* ws = (float*)d_ws;
  // Workspace layout (floats). Total 112,887,580 floats = 451.6 MB.
  float* rel = ws;                            // 4096*16900 = 69,222,400  (rel_pre, then A in place)
  float* qk  = ws + 69222400;                 // 4096*8320  = 34,078,720  (dead after k_rel)
  float* xw1 = ws + 103301120;                // 4096*2080  =  8,519,680
  float* sp  = ws + 111820800;                // 2*130*4096 =  1,064,960  (per-stage partials, reused)
  float* ac  = ws + 112885760;                // 7*260 affine params
  // Z buffers alias the (dead) qk region:
  float* Z1 = qk;                             // 8,519,680
  float* Z2 = qk + 8519680;                   // 8,519,680
  float* Z3 = qk + 17039360;                  // 2,129,920
  float* Z4 = qk + 19169280;                  // 2,129,920
  float* Z5 = qk + 21299200;                  // 1,064,960
  float* Z6 = qk + 22364160;                  // 1,064,960

  k_in<<<8320, 256, 0, stream>>>(X, WQ, BQ, W1, qk, xw1);
  k_rel<<<4096, 256, 0, stream>>>(qk, rel, sp);
  k_stats<<<130, 256, 0, stream>>>(sp, GT, BT, 1.f / 532480.f, ac);          // bn_t: N=B*R
  k_A<<<4096, 256, 0, stream>>>(rel, xw1, ac, Bb1, THR, Z1, sp);
  k_stats<<<130, 256, 0, stream>>>(sp, G1, BE1, 1.f / 65536.f, ac + 260);    // bn1: N=B*16
  k_gcn<16, 16, false><<<4096, 256, 0, stream>>>(rel, Z1, nullptr, ac + 260, nullptr, W2, Bb2, Z2, sp);
  k_stats<<<130, 256, 0, stream>>>(sp, G2, BE2, 1.f / 65536.f, ac + 520);    // bn2
  k_gcn<16, 4, true><<<4096, 256, 0, stream>>>(rel, Z2, Z1, ac + 520, ac + 260, W3, Bb3, Z3, sp);
  k_stats<<<130, 256, 0, stream>>>(sp, G3, BE3, 1.f / 16384.f, ac + 780);    // bn3: N=B*4
  k_gcn<4, 4, false><<<4096, 256, 0, stream>>>(rel, Z3, nullptr, ac + 780, nullptr, W4, Bb4, Z4, sp);
  k_stats<<<130, 256, 0, stream>>>(sp, G4, BE4, 1.f / 16384.f, ac + 1040);   // bn4
  k_gcn<4, 2, true><<<4096, 256, 0, stream>>>(rel, Z4, Z3, ac + 1040, ac + 780, W5, Bb5, Z5, sp);
  k_stats<<<130, 256, 0, stream>>>(sp, G5, BE5, 1.f / 8192.f, ac + 1300);    // bn5: N=B*2
  k_gcn<2, 2, false><<<4096, 256, 0, stream>>>(rel, Z5, nullptr, ac + 1300, nullptr, W6, Bb6, Z6, sp);
  k_stats<<<130, 256, 0, stream>>>(sp, G6, BE6, 1.f / 8192.f, ac + 1560);    // bn6
  k_mlp<<<1024, 256, 0, stream>>>(Z5, Z6, ac + 1300, ac + 1560, WM, BM, (float*)d_out);
}

// Round 2
// 1247.723 us; speedup vs baseline: 2.6877x; 2.6877x over previous
//
#include <hip/hip_runtime.h>
#include <math.h>

// B=4096, R=130, T=200, Q=64. All heavy matmuls in f16 MFMA 16x16x32, fp32 accum.
// BN folded to per-row affine a*x+c; stats via fp32 partials (deterministic).
// rel is never materialized in fp32: k_relstats emits stats only; k_Asoft
// recomputes tiles, online-softmaxes, stores A as fp16 [b][130][136] (cols
// 130-135 zeroed so consumers can copy in half8 chunks).

typedef _Float16 f16;
typedef _Float16 f16x8 __attribute__((ext_vector_type(8)));
typedef _Float16 f16x4 __attribute__((ext_vector_type(4)));
typedef float f32x4 __attribute__((ext_vector_type(4)));

#define MFMA16(a, b, c) __builtin_amdgcn_mfma_f32_16x16x32_f16((a), (b), (c), 0, 0, 0)

// ---------------- k_in: X(532480x200) @ [wq|w1]^T(200x80) -> qk f16, xw1 f16
__global__ __launch_bounds__(256) void k_in(
    const float* __restrict__ x, const float* __restrict__ wq,
    const float* __restrict__ w1, const float* __restrict__ bq,
    f16* __restrict__ qk, f16* __restrict__ xw1)
{
  __shared__ f16 xs[64 * 224];                // 64 rows, K padded 200->224 (zeros)
  __shared__ f16 ws[80 * 224];                // 80 weight rows (64 wq + 16 w1)
  const int tid = threadIdx.x;
  const size_t m0 = (size_t)blockIdx.x * 64;  // 8320 blocks
  // zero K-pad cols 200-223
  for (int i = tid; i < 192; i += 256) {      // 64*3 half8 units
    int r = i / 3, j = i - (i / 3) * 3;
    *(float4*)&xs[r * 224 + 200 + j * 8] = make_float4(0, 0, 0, 0);
  }
  for (int i = tid; i < 240; i += 256) {      // 80*3
    int r = i / 3, j = i - (i / 3) * 3;
    *(float4*)&ws[r * 224 + 200 + j * 8] = make_float4(0, 0, 0, 0);
  }
  // stage X tile (NaN-clean, cvt f16)
  const float4* xsrc = (const float4*)(x + m0 * 200);
  for (int i = tid; i < 3200; i += 256) {
    int r = i / 50, c = i - (i / 50) * 50;
    float4 v = xsrc[i];
    v.x = (v.x != v.x) ? 0.f : v.x;
    v.y = (v.y != v.y) ? 0.f : v.y;
    v.z = (v.z != v.z) ? 0.f : v.z;
    v.w = (v.w != v.w) ? 0.f : v.w;
    f16x4 h; h[0] = (f16)v.x; h[1] = (f16)v.y; h[2] = (f16)v.z; h[3] = (f16)v.w;
    *(f16x4*)&xs[r * 224 + c * 4] = h;
  }
  // stage weights (L2-hot across blocks)
  for (int i = tid; i < 4000; i += 256) {
    int f = i / 50, c = i - (i / 50) * 50;
    const float4* src = (f < 64) ? (const float4*)(wq + f * 200) + c
                                 : (const float4*)(w1 + (f - 64) * 200) + c;
    float4 v = *src;
    f16x4 h; h[0] = (f16)v.x; h[1] = (f16)v.y; h[2] = (f16)v.z; h[3] = (f16)v.w;
    *(f16x4*)&ws[f * 224 + c * 4] = h;
  }
  __syncthreads();
  const int lane = tid & 63, wv = tid >> 6;
  const int mrow = lane & 15, quad = lane >> 4;
  f32x4 acc[5];
#pragma unroll
  for (int n = 0; n < 5; n++) acc[n] = (f32x4){0.f, 0.f, 0.f, 0.f};
  const f16* xrow = &xs[(wv * 16 + mrow) * 224 + quad * 8];
#pragma unroll
  for (int k0 = 0; k0 < 224; k0 += 32) {
    f16x8 af = *(const f16x8*)(xrow + k0);
#pragma unroll
    for (int n = 0; n < 5; n++) {
      f16x8 bf = *(const f16x8*)&ws[(n * 16 + mrow) * 224 + k0 + quad * 8];
      acc[n] = MFMA16(af, bf, acc[n]);
    }
  }
  const size_t rbase = m0 + wv * 16;
#pragma unroll
  for (int n = 0; n < 4; n++) {               // qk (+bq), cols 0-63
    int col = n * 16 + mrow;
    float bqv = bq[col];
#pragma unroll
    for (int i = 0; i < 4; i++)
      qk[(rbase + quad * 4 + i) * 64 + col] = (f16)(acc[n][i] + bqv);
  }
#pragma unroll
  for (int i = 0; i < 4; i++)                 // xw1, NO bias (added post-A-matmul)
    xw1[(rbase + quad * 4 + i) * 16 + mrow] = (f16)acc[4][i];
}

// ---------------- shared staging for rel tiles: Qm[144x72], Kt[144x72] f16
__device__ __forceinline__ void stage_qkt(const f16* qb, f16* Qm, f16* Kt, int tid)
{
  for (int i = tid; i < 1040; i += 256) {     // Qm rows 0-129 contiguous
    int r = i >> 3, j = i & 7;
    *(f16x8*)&Qm[r * 72 + j * 8] = *(const f16x8*)(qb + i * 8);
  }
  for (int i = tid; i < 126; i += 256) {      // zero rows 130-143 of both
    int r = 130 + i / 9, j = i - (i / 9) * 9;
    *(float4*)&Qm[r * 72 + j * 8] = make_float4(0, 0, 0, 0);
    *(float4*)&Kt[r * 72 + j * 8] = make_float4(0, 0, 0, 0);
  }
  for (int i = tid; i < 8320; i += 256) {     // Kt[s][q] = flat[q*130+s] (faithful reshape)
    int q = i / 130, s = i - (i / 130) * 130;
    Kt[s * 72 + q] = qb[i];
  }
}

// ---------------- k_relstats: rel tiles (MFMA), emit BN partial sums only
__global__ __launch_bounds__(256) void k_relstats(
    const f16* __restrict__ qk, float* __restrict__ sp)
{
  __shared__ f16 Qm[144 * 72];
  __shared__ f16 Kt[144 * 72];
  const int b = blockIdx.x, tid = threadIdx.x;
  stage_qkt(qk + (size_t)b * 8320, Qm, Kt, tid);
  __syncthreads();
  const int lane = tid & 63, wv = tid >> 6, mrow = lane & 15, quad = lane >> 4;
  for (int m = wv; m < 9; m += 4) {
    float p1[4] = {0, 0, 0, 0}, p2[4] = {0, 0, 0, 0};
    const f16* arow = &Qm[(m * 16 + mrow) * 72 + quad * 8];
    f16x8 af0 = *(const f16x8*)arow;
    f16x8 af1 = *(const f16x8*)(arow + 32);
    for (int n = 0; n < 9; n++) {
      const f16* brow = &Kt[(n * 16 + mrow) * 72 + quad * 8];
      f32x4 acc = (f32x4){0.f, 0.f, 0.f, 0.f};
      acc = MFMA16(af0, *(const f16x8*)brow, acc);
      acc = MFMA16(af1, *(const f16x8*)(brow + 32), acc);
#pragma unroll
      for (int i = 0; i < 4; i++) { float v = acc[i]; p1[i] += v; p2[i] += v * v; }
    }
#pragma unroll
    for (int i = 0; i < 4; i++)
#pragma unroll
      for (int msk = 1; msk <= 8; msk <<= 1) {
        p1[i] += __shfl_xor(p1[i], msk); p2[i] += __shfl_xor(p2[i], msk);
      }
    if (mrow == 0) {
#pragma unroll
      for (int i = 0; i < 4; i++) {
        int r = m * 16 + quad * 4 + i;
        if (r < 130) {
          sp[(size_t)r * 4096 + b] = p1[i];
          sp[130 * 4096 + (size_t)r * 4096 + b] = p2[i];
        }
      }
    }
  }
}

// ---------------- k_stats: reduce partials -> affine a,c (unchanged, fp32)
__global__ __launch_bounds__(256) void k_stats(
    const float* __restrict__ sp, const float* __restrict__ g,
    const float* __restrict__ beta, float invN, float* __restrict__ ac)
{
  const int r = blockIdx.x, tid = threadIdx.x;
  float s1 = 0.f, s2 = 0.f;
  const float* p1 = sp + (size_t)r * 4096;
  const float* p2 = sp + 130 * 4096 + (size_t)r * 4096;
  for (int j = tid; j < 4096; j += 256) { s1 += p1[j]; s2 += p2[j]; }
#pragma unroll
  for (int m = 1; m <= 32; m <<= 1) { s1 += __shfl_xor(s1, m); s2 += __shfl_xor(s2, m); }
  __shared__ float r1[4], r2[4];
  if ((tid & 63) == 0) { r1[tid >> 6] = s1; r2[tid >> 6] = s2; }
  __syncthreads();
  if (tid == 0) {
    float S1 = r1[0] + r1[1] + r1[2] + r1[3];
    float S2 = r2[0] + r2[1] + r2[2] + r2[3];
    float mean = S1 * invN;
    float var = S2 * invN - mean * mean;
    float a = g[r] * rsqrtf(var + 1e-5f);
    ac[r] = a;
    ac[130 + r] = beta[r] - mean * a;
  }
}

// ---------------- k_Asoft: recompute rel, affine, online softmax, relu-thr, A->f16
__global__ __launch_bounds__(256) void k_Asoft(
    const f16* __restrict__ qk, const float* __restrict__ ac0,
    const float* __restrict__ thrp, f16* __restrict__ A16)
{
  __shared__ f16 Qm[144 * 72];
  __shared__ f16 Kt[144 * 72];
  const int b = blockIdx.x, tid = threadIdx.x;
  stage_qkt(qk + (size_t)b * 8320, Qm, Kt, tid);
  __syncthreads();
  const float thr = *thrp;
  const int lane = tid & 63, wv = tid >> 6, mrow = lane & 15, quad = lane >> 4;
  f16* Ab = A16 + (size_t)b * 17680;          // row stride 136
  for (int m = wv; m < 9; m += 4) {
    float a4[4], c4[4];
#pragma unroll
    for (int i = 0; i < 4; i++) {
      int r = m * 16 + quad * 4 + i;
      a4[i] = (r < 130) ? ac0[r] : 0.f;
      c4[i] = (r < 130) ? ac0[130 + r] : 0.f;
    }
    const f16* arow = &Qm[(m * 16 + mrow) * 72 + quad * 8];
    f16x8 af0 = *(const f16x8*)arow;
    f16x8 af1 = *(const f16x8*)(arow + 32);
    float mx[4] = {-3e38f, -3e38f, -3e38f, -3e38f}, sm[4] = {0, 0, 0, 0};
    for (int n = 0; n < 9; n++) {             // pass 1: online max/sum
      const f16* brow = &Kt[(n * 16 + mrow) * 72 + quad * 8];
      f32x4 acc = (f32x4){0.f, 0.f, 0.f, 0.f};
      acc = MFMA16(af0, *(const f16x8*)brow, acc);
      acc = MFMA16(af1, *(const f16x8*)(brow + 32), acc);
      const bool valid = (n * 16 + mrow) < 130;
#pragma unroll
      for (int i = 0; i < 4; i++) {
        float v = a4[i] * acc[i] + c4[i];
        float ve = valid ? v : -3e38f;
        float nm = fmaxf(mx[i], ve);
        sm[i] = sm[i] * __expf(mx[i] - nm) + (valid ? __expf(v - nm) : 0.f);
        mx[i] = nm;
      }
    }
#pragma unroll
    for (int i = 0; i < 4; i++) {             // quad (16-lane) softmax-state reduce
#pragma unroll
      for (int msk = 1; msk <= 8; msk <<= 1) {
        float om = __shfl_xor(mx[i], msk), os = __shfl_xor(sm[i], msk);
        float nm = fmaxf(mx[i], om);
        sm[i] = sm[i] * __expf(mx[i] - nm) + os * __expf(om - nm);
        mx[i] = nm;
      }
      sm[i] = 1.f / sm[i];                    // invS
    }
    for (int n = 0; n < 9; n++) {             // pass 2: recompute, emit A f16
      const f16* brow = &Kt[(n * 16 + mrow) * 72 + quad * 8];
      f32x4 acc = (f32x4){0.f, 0.f, 0.f, 0.f};
      acc = MFMA16(af0, *(const f16x8*)brow, acc);
      acc = MFMA16(af1, *(const f16x8*)(brow + 32), acc);
      const int col = n * 16 + mrow;
#pragma unroll
      for (int i = 0; i < 4; i++) {
        int r = m * 16 + quad * 4 + i;
        if (r < 130) {
          if (col < 130) {
            float v = a4[i] * acc[i] + c4[i];
            float Av = fmaxf(__expf(v - mx[i]) * sm[i] - thr, 0.f);
            Ab[r * 136 + col] = (f16)Av;
          } else if (col < 136) {
            Ab[r * 136 + col] = (f16)0.f;     // keep packed rows zero-padded
          }
        }
      }
    }
  }
}

// ---------------- k_gcn: Z = A @ g + b (MFMA); g from xw1 (G1) or affine+relu+W
template <int FI, int FO, bool RES, bool G1>
__global__ __launch_bounds__(256) void k_gcn(
    const f16* __restrict__ A16, const float* __restrict__ ZP,
    const float* __restrict__ ZQ, const f16* __restrict__ xw1,
    const float* __restrict__ acP, const float* __restrict__ acQ,
    const float* __restrict__ wmat, const float* __restrict__ bb,
    float* __restrict__ Zout, float* __restrict__ sp)
{
  __shared__ f16 Ald[144 * 160];              // A, K padded to 160 (cols 136+ zeroed)
  __shared__ f16 gT[16 * 160];                // g^T[n][k], zero-padded
  const int b = blockIdx.x, tid = threadIdx.x;
  const f16* Ab = A16 + (size_t)b * 17680;
  for (int i = tid; i < 2210; i += 256) {     // 130 rows x 17 half8 chunks
    int r = i / 17, c8 = i - (i / 17) * 17;
    *(f16x8*)&Ald[r * 160 + c8 * 8] = *(const f16x8*)(Ab + r * 136 + c8 * 8);
  }
  for (int i = tid; i < 432; i += 256) {      // zero cols 136-159, all 144 rows
    int r = i / 3, j = i - (i / 3) * 3;
    *(float4*)&Ald[r * 160 + 136 + j * 8] = make_float4(0, 0, 0, 0);
  }
  for (int i = tid; i < 320; i += 256)        // zero gT
    ((float4*)gT)[i] = make_float4(0, 0, 0, 0);
  __syncthreads();
  if constexpr (G1) {
    for (int i = tid; i < 2080; i += 256) {
      int s = i >> 4, f = i & 15;
      gT[f * 160 + s] = xw1[(size_t)b * 2080 + i];
    }
  } else {
    if (tid < 130) {
      const int r = tid;
      float h[FI];
      const float* zp = ZP + ((size_t)b * 130 + r) * FI;
      const float aP = acP[r], cP = acP[130 + r];
#pragma unroll
      for (int i = 0; i < FI; i++) h[i] = fmaxf(aP * zp[i] + cP, 0.f);
      if constexpr (RES) {
        const float* zq = ZQ + ((size_t)b * 130 + r) * FI;
        const float aQ = acQ[r], cQ = acQ[130 + r];
#pragma unroll
        for (int i = 0; i < FI; i++) h[i] += fmaxf(aQ * zq[i] + cQ, 0.f);
      }
#pragma unroll
      for (int k = 0; k < FO; k++) {
        float s = 0.f;
#pragma unroll
        for (int i = 0; i < FI; i++) s += h[i] * wmat[k * FI + i];
        gT[k * 160 + r] = (f16)s;             // bias NOT here (added post-A)
      }
    }
  }
  __syncthreads();
  const int lane = tid & 63, wv = tid >> 6, mrow = lane & 15, quad = lane >> 4;
  for (int m = wv; m < 9; m += 4) {
    f32x4 acc = (f32x4){0.f, 0.f, 0.f, 0.f};
    const f16* arow = &Ald[(m * 16 + mrow) * 160];
    const f16* brow = &gT[mrow * 160];
#pragma unroll
    for (int k0 = 0; k0 < 160; k0 += 32) {
      f16x8 af = *(const f16x8*)(arow + k0 + quad * 8);
      f16x8 bf = *(const f16x8*)(brow + k0 + quad * 8);
      acc = MFMA16(af, bf, acc);
    }
    const int col = mrow;
    const float bk = (col < FO) ? bb[col] : 0.f;
    float p1[4], p2[4];
#pragma unroll
    for (int i = 0; i < 4; i++) {
      int r = m * 16 + quad * 4 + i;
      float v = (col < FO) ? acc[i] + bk : 0.f;
      if (col < FO && r < 130)
        Zout[((size_t)b * 130 + r) * FO + col] = v;
      p1[i] = v; p2[i] = v * v;
    }
#pragma unroll
    for (int i = 0; i < 4; i++)
#pragma unroll
      for (int msk = 1; msk <= 8; msk <<= 1) {
        p1[i] += __shfl_xor(p1[i], msk); p2[i] += __shfl_xor(p2[i], msk);
      }
    if (mrow == 0) {
#pragma unroll
      for (int i = 0; i < 4; i++) {
        int r = m * 16 + quad * 4 + i;
        if (r < 130) {
          sp[(size_t)r * 4096 + b] = p1[i];
          sp[130 * 4096 + (size_t)r * 4096 + b] = p2[i];
        }
      }
    }
  }
}

// ---------------- k_mlp (unchanged)
__global__ __launch_bounds__(256) void k_mlp(
    const float* __restrict__ Z5, const float* __restrict__ Z6,
    const float* __restrict__ ac5, const float* __restrict__ ac6,
    const float* __restrict__ wm, const float* __restrict__ bm, float* __restrict__ out)
{
  const int tid = threadIdx.x, lane = tid & 63, wv = tid >> 6;
  const int b = blockIdx.x * 4 + wv;
  const float* z5 = Z5 + (size_t)b * 260;
  const float* z6 = Z6 + (size_t)b * 260;
  float p0 = 0.f, p1 = 0.f;
#pragma unroll
  for (int j = 0; j < 5; j++) {
    int i = lane + 64 * j;
    if (i < 260) {
      int r = i >> 1;
      float h = fmaxf(ac6[r] * z6[i] + ac6[130 + r], 0.f)
              + fmaxf(ac5[r] * z5[i] + ac5[130 + r], 0.f);
      p0 += h * wm[i];
      p1 += h * wm[260 + i];
    }
  }
#pragma unroll
  for (int m = 1; m <= 32; m <<= 1) { p0 += __shfl_xor(p0, m); p1 += __shfl_xor(p1, m); }
  if (lane == 0) {
    out[(size_t)b * 2] = fmaxf(p0 + bm[0], 0.f);
    out[(size_t)b * 2 + 1] = fmaxf(p1 + bm[1], 0.f);
  }
}

extern "C" void kernel_launch(void* const* d_in, const int* in_sizes, int n_in,
                              void* d_out, int out_size, void* d_ws, size_t ws_size,
                              hipStream_t stream) {
  const float* X   = (const float*)d_in[0];
  const float* THR = (const float*)d_in[1];
  const float* WQ  = (const float*)d_in[2];
  const float* BQ  = (const float*)d_in[3];
  const float* GT  = (const float*)d_in[4];
  const float* BT  = (const float*)d_in[5];
  const float* W1 = (const float*)d_in[6];  const float* Bb1 = (const float*)d_in[7];
  const float* G1g = (const float*)d_in[8]; const float* BE1 = (const float*)d_in[9];
  const float* W2 = (const float*)d_in[10]; const float* Bb2 = (const float*)d_in[11];
  const float* G2 = (const float*)d_in[12]; const float* BE2 = (const float*)d_in[13];
  const float* W3 = (const float*)d_in[14]; const float* Bb3 = (const float*)d_in[15];
  const float* G3 = (const float*)d_in[16]; const float* BE3 = (const float*)d_in[17];
  const float* W4 = (const float*)d_in[18]; const float* Bb4 = (const float*)d_in[19];
  const float* G4 = (const float*)d_in[20]; const float* BE4 = (const float*)d_in[21];
  const float* W5 = (const float*)d_in[22]; const float* Bb5 = (const float*)d_in[23];
  const float* G5 = (const float*)d_in[24]; const float* BE5 = (const float*)d_in[25];
  const float* W6 = (const float*)d_in[26]; const float* Bb6 = (const float*)d_in[27];
  const float* G6 = (const float*)d_in[28]; const float* BE6 = (const float*)d_in[29];
  const float* WM = (const float*)d_in[30]; const float* BM = (const float*)d_in[31];

  float* ws = (float*)d_ws;
  // Workspace (float units). Total 82,003,740 floats = 328 MB.
  f16*   A16   = (f16*)ws;                    // 4096*130*136 halfs (36,208,640 fl)
  f16*   qk16  = (f16*)(ws + 36208640);       // 532480*64 halfs   (17,039,360 fl)
  f16*   xw116 = (f16*)(ws + 53248000);       // 532480*16 halfs   ( 4,259,840 fl)
  float* Z1 = ws + 57507840;                  // 4096*130*16
  float* Z2 = ws + 66027520;                  // 4096*130*16
  float* Z3 = ws + 74547200;                  // 4096*130*4
  float* Z4 = ws + 76677120;                  // 4096*130*4
  float* Z5 = ws + 78807040;                  // 4096*130*2
  float* Z6 = ws + 79872000;                  // 4096*130*2
  float* sp = ws + 80936960;                  // 2*130*4096
  float* ac = ws + 82001920;                  // 7*260

  k_in<<<8320, 256, 0, stream>>>(X, WQ, W1, BQ, qk16, xw116);
  k_relstats<<<4096, 256, 0, stream>>>(qk16, sp);
  k_stats<<<130, 256, 0, stream>>>(sp, GT, BT, 1.f / 532480.f, ac);
  k_Asoft<<<4096, 256, 0, stream>>>(qk16, ac, THR, A16);
  k_gcn<16, 16, false, true><<<4096, 256, 0, stream>>>(A16, nullptr, nullptr, xw116,
      nullptr, nullptr, nullptr, Bb1, Z1, sp);
  k_stats<<<130, 256, 0, stream>>>(sp, G1g, BE1, 1.f / 65536.f, ac + 260);
  k_gcn<16, 16, false, false><<<4096, 256, 0, stream>>>(A16, Z1, nullptr, nullptr,
      ac + 260, nullptr, W2, Bb2, Z2, sp);
  k_stats<<<130, 256, 0, stream>>>(sp, G2, BE2, 1.f / 65536.f, ac + 520);
  k_gcn<16, 4, true, false><<<4096, 256, 0, stream>>>(A16, Z2, Z1, nullptr,
      ac + 520, ac + 260, W3, Bb3, Z3, sp);
  k_stats<<<130, 256, 0, stream>>>(sp, G3, BE3, 1.f / 16384.f, ac + 780);
  k_gcn<4, 4, false, false><<<4096, 256, 0, stream>>>(A16, Z3, nullptr, nullptr,
      ac + 780, nullptr, W4, Bb4, Z4, sp);
  k_stats<<<130, 256, 0, stream>>>(sp, G4, BE4, 1.f / 16384.f, ac + 1040);
  k_gcn<4, 2, true, false><<<4096, 256, 0, stream>>>(A16, Z4, Z3, nullptr,
      ac + 1040, ac + 780, W5, Bb5, Z5, sp);
  k_stats<<<130, 256, 0, stream>>>(sp, G5, BE5, 1.f / 8192.f, ac + 1300);
  k_gcn<2, 2, false, false><<<4096, 256, 0, stream>>>(A16, Z5, nullptr, nullptr,
      ac + 1300, nullptr, W6, Bb6, Z6, sp);
  k_stats<<<130, 256, 0, stream>>>(sp, G6, BE6, 1.f / 8192.f, ac + 1560);
  k_mlp<<<1024, 256, 0, stream>>>(Z5, Z6, ac + 1300, ac + 1560, WM, BM, (float*)d_out);
}

// Round 3
// 1133.932 us; speedup vs baseline: 2.9574x; 1.1004x over previous
//
#include <hip/hip_runtime.h>
#include <math.h>

// B=4096, R=130, T=200, Q=64. f16 MFMA 16x16x32 everywhere, fp32 accum/stats.
// Design notes (R3): no LDS staging for operands without intra-block reuse.
//  - k_in: X tile in LDS (stride 232 halves -> conflict-free), weights f16 in
//    global (w_prep), B-frags read from L2.
//  - k_relstats/k_Asoft: flat qk in LDS; B-frags gathered once into VGPRs;
//    A-frags direct from global; k_Asoft single MFMA pass (9 acc tiles in regs).
//  - k_gcn: A-frags direct from global (no reuse); only 16x168 gT in LDS.

typedef _Float16 f16;
typedef _Float16 f16x8 __attribute__((ext_vector_type(8)));
typedef _Float16 f16x4 __attribute__((ext_vector_type(4)));
typedef float f32x4 __attribute__((ext_vector_type(4)));

#define MFMA16(a, b, c) __builtin_amdgcn_mfma_f32_16x16x32_f16((a), (b), (c), 0, 0, 0)

// ---------------- w_prep: [wq(64x200) | w1(16x200)] -> f16 wf[80][224], K zero-pad
__global__ __launch_bounds__(256) void w_prep(
    const float* __restrict__ wq, const float* __restrict__ w1, f16* __restrict__ wf)
{
  const int f = blockIdx.x;                   // 80 blocks
  const int k = threadIdx.x;
  if (k < 224) {
    float v = 0.f;
    if (k < 200) v = (f < 64) ? wq[f * 200 + k] : w1[(f - 64) * 200 + k];
    wf[f * 224 + k] = (f16)v;
  }
}

// ---------------- k_in: X(532480x200) @ wf^T -> qk f16 (B,130,64), xw1 f16 (B,130,16)
__global__ __launch_bounds__(256) void k_in(
    const float* __restrict__ x, const f16* __restrict__ wf,
    const float* __restrict__ bq, f16* __restrict__ qk, f16* __restrict__ xw1)
{
  __shared__ f16 xs[64 * 232];                // stride 232 halves = 464B == 20 banks: 2-way free
  const int tid = threadIdx.x;
  const size_t m0 = (size_t)blockIdx.x * 64;  // 8320 blocks
  {                                           // zero K-pad cols 200..231 (exactly 256 stores)
    int r = tid >> 2, j = tid & 3;
    *(float4*)&xs[r * 232 + 200 + j * 8] = make_float4(0, 0, 0, 0);
  }
  const float4* xsrc = (const float4*)(x + m0 * 200);
  for (int i = tid; i < 3200; i += 256) {     // NaN-clean + cvt f16
    int r = i / 50, c = i - (i / 50) * 50;
    float4 v = xsrc[i];
    v.x = (v.x != v.x) ? 0.f : v.x;
    v.y = (v.y != v.y) ? 0.f : v.y;
    v.z = (v.z != v.z) ? 0.f : v.z;
    v.w = (v.w != v.w) ? 0.f : v.w;
    f16x4 h; h[0] = (f16)v.x; h[1] = (f16)v.y; h[2] = (f16)v.z; h[3] = (f16)v.w;
    *(f16x4*)&xs[r * 232 + c * 4] = h;
  }
  __syncthreads();
  const int lane = tid & 63, wv = tid >> 6;
  const int mrow = lane & 15, quad = lane >> 4;
  f32x4 acc[5];
#pragma unroll
  for (int n = 0; n < 5; n++) acc[n] = (f32x4){0.f, 0.f, 0.f, 0.f};
  const f16* xrow = &xs[(wv * 16 + mrow) * 232 + quad * 8];
  const f16* wrow = wf + mrow * 224 + quad * 8;   // B-frags from global (L2-hot)
#pragma unroll
  for (int k0 = 0; k0 < 224; k0 += 32) {
    f16x8 af = *(const f16x8*)(xrow + k0);
#pragma unroll
    for (int n = 0; n < 5; n++)
      acc[n] = MFMA16(af, *(const f16x8*)(wrow + n * 3584 + k0), acc[n]);
  }
  const size_t rbase = m0 + wv * 16;
#pragma unroll
  for (int n = 0; n < 4; n++) {               // qk (+bq)
    int col = n * 16 + mrow;
    float bqv = bq[col];
#pragma unroll
    for (int i = 0; i < 4; i++)
      qk[(rbase + quad * 4 + i) * 64 + col] = (f16)(acc[n][i] + bqv);
  }
#pragma unroll
  for (int i = 0; i < 4; i++)                 // xw1, no bias (added post-A-matmul)
    xw1[(rbase + quad * 4 + i) * 16 + mrow] = (f16)acc[4][i];
}

// Gather the 18 B-fragments (9 n-tiles x 2 k-halves) for the reshape-K matmul.
// B[k=q][n-col=s]: element = flat[q*130+s]; s>=130 -> 0.
__device__ __forceinline__ void gather_bfrags(const f16* qf, int mrow, int quad,
                                              f16x8 bf[9][2])
{
#pragma unroll
  for (int n = 0; n < 9; n++) {
    const int s = n * 16 + mrow;
    const bool ok = (s < 130);
#pragma unroll
    for (int kh = 0; kh < 2; kh++) {
      f16x8 t;
#pragma unroll
      for (int j = 0; j < 8; j++) {
        int q = kh * 32 + quad * 8 + j;
        t[j] = ok ? qf[q * 130 + s] : (f16)0.f;
      }
      bf[n][kh] = t;
    }
  }
}

// ---------------- k_relstats: rel tiles (MFMA), emit BN partial sums only
__global__ __launch_bounds__(256) void k_relstats(
    const f16* __restrict__ qk, float* __restrict__ sp)
{
  __shared__ f16 qf[8320];                    // flat per-batch qk (16.6 KB)
  const int b = blockIdx.x, tid = threadIdx.x;
  const f16* qb = qk + (size_t)b * 8320;
  for (int i = tid; i < 1040; i += 256)
    *(f16x8*)&qf[i * 8] = *(const f16x8*)(qb + i * 8);
  __syncthreads();
  const int lane = tid & 63, wv = tid >> 6, mrow = lane & 15, quad = lane >> 4;
  f16x8 bf[9][2];
  gather_bfrags(qf, mrow, quad, bf);
  for (int m = wv; m < 9; m += 4) {
    const f16* arow = qb + (m * 16 + mrow) * 64 + quad * 8;   // direct global
    f16x8 af0 = *(const f16x8*)arow;
    f16x8 af1 = *(const f16x8*)(arow + 32);
    float p1[4] = {0, 0, 0, 0}, p2[4] = {0, 0, 0, 0};
#pragma unroll
    for (int n = 0; n < 9; n++) {
      f32x4 acc = (f32x4){0.f, 0.f, 0.f, 0.f};
      acc = MFMA16(af0, bf[n][0], acc);
      acc = MFMA16(af1, bf[n][1], acc);
#pragma unroll
      for (int i = 0; i < 4; i++) { float v = acc[i]; p1[i] += v; p2[i] += v * v; }
    }
#pragma unroll
    for (int i = 0; i < 4; i++)
#pragma unroll
      for (int msk = 1; msk <= 8; msk <<= 1) {
        p1[i] += __shfl_xor(p1[i], msk); p2[i] += __shfl_xor(p2[i], msk);
      }
    if (mrow == 0) {
#pragma unroll
      for (int i = 0; i < 4; i++) {
        int r = m * 16 + quad * 4 + i;
        if (r < 130) {
          sp[(size_t)r * 4096 + b] = p1[i];
          sp[130 * 4096 + (size_t)r * 4096 + b] = p2[i];
        }
      }
    }
  }
}

// ---------------- k_stats: reduce partials -> affine a,c
__global__ __launch_bounds__(256) void k_stats(
    const float* __restrict__ sp, const float* __restrict__ g,
    const float* __restrict__ beta, float invN, float* __restrict__ ac)
{
  const int r = blockIdx.x, tid = threadIdx.x;
  float s1 = 0.f, s2 = 0.f;
  const float* p1 = sp + (size_t)r * 4096;
  const float* p2 = sp + 130 * 4096 + (size_t)r * 4096;
  for (int j = tid; j < 4096; j += 256) { s1 += p1[j]; s2 += p2[j]; }
#pragma unroll
  for (int m = 1; m <= 32; m <<= 1) { s1 += __shfl_xor(s1, m); s2 += __shfl_xor(s2, m); }
  __shared__ float r1[4], r2[4];
  if ((tid & 63) == 0) { r1[tid >> 6] = s1; r2[tid >> 6] = s2; }
  __syncthreads();
  if (tid == 0) {
    float S1 = r1[0] + r1[1] + r1[2] + r1[3];
    float S2 = r2[0] + r2[1] + r2[2] + r2[3];
    float mean = S1 * invN;
    float var = S2 * invN - mean * mean;
    float a = g[r] * rsqrtf(var + 1e-5f);
    ac[r] = a;
    ac[130 + r] = beta[r] - mean * a;
  }
}

// ---------------- k_Asoft: rel (1 MFMA pass, 9 acc tiles in regs), affine,
// softmax, relu(x-thr), A -> f16 [b][130][136] (cols 130-135 zeroed)
__global__ __launch_bounds__(256) void k_Asoft(
    const f16* __restrict__ qk, const float* __restrict__ ac0,
    const float* __restrict__ thrp, f16* __restrict__ A16)
{
  __shared__ f16 qf[8320];
  const int b = blockIdx.x, tid = threadIdx.x;
  const f16* qb = qk + (size_t)b * 8320;
  for (int i = tid; i < 1040; i += 256)
    *(f16x8*)&qf[i * 8] = *(const f16x8*)(qb + i * 8);
  __syncthreads();
  const float thr = *thrp;
  const int lane = tid & 63, wv = tid >> 6, mrow = lane & 15, quad = lane >> 4;
  f16x8 bf[9][2];
  gather_bfrags(qf, mrow, quad, bf);
  f16* Ab = A16 + (size_t)b * 17680;          // row stride 136
  for (int m = wv; m < 9; m += 4) {
    float a4[4], c4[4];
#pragma unroll
    for (int i = 0; i < 4; i++) {
      int r = m * 16 + quad * 4 + i;
      a4[i] = (r < 130) ? ac0[r] : 0.f;
      c4[i] = (r < 130) ? ac0[130 + r] : 0.f;
    }
    const f16* arow = qb + (m * 16 + mrow) * 64 + quad * 8;
    f16x8 af0 = *(const f16x8*)arow;
    f16x8 af1 = *(const f16x8*)(arow + 32);
    f32x4 acc[9];
#pragma unroll
    for (int n = 0; n < 9; n++) {
      acc[n] = (f32x4){0.f, 0.f, 0.f, 0.f};
      acc[n] = MFMA16(af0, bf[n][0], acc[n]);
      acc[n] = MFMA16(af1, bf[n][1], acc[n]);
    }
    float mx[4] = {-3e38f, -3e38f, -3e38f, -3e38f}, sm[4] = {0, 0, 0, 0};
#pragma unroll
    for (int n = 0; n < 9; n++) {             // online max/sum over cols
      const bool valid = (n * 16 + mrow) < 130;
#pragma unroll
      for (int i = 0; i < 4; i++) {
        float v = a4[i] * acc[n][i] + c4[i];
        float ve = valid ? v : -3e38f;
        float nm = fmaxf(mx[i], ve);
        sm[i] = sm[i] * __expf(mx[i] - nm) + (valid ? __expf(v - nm) : 0.f);
        mx[i] = nm;
      }
    }
#pragma unroll
    for (int i = 0; i < 4; i++) {             // 16-lane softmax-state reduce
#pragma unroll
      for (int msk = 1; msk <= 8; msk <<= 1) {
        float om = __shfl_xor(mx[i], msk), os = __shfl_xor(sm[i], msk);
        float nm = fmaxf(mx[i], om);
        sm[i] = sm[i] * __expf(mx[i] - nm) + os * __expf(om - nm);
        mx[i] = nm;
      }
      sm[i] = 1.f / sm[i];
    }
#pragma unroll
    for (int n = 0; n < 9; n++) {             // emit A f16
      const int col = n * 16 + mrow;
#pragma unroll
      for (int i = 0; i < 4; i++) {
        int r = m * 16 + quad * 4 + i;
        if (r < 130) {
          if (col < 130) {
            float v = a4[i] * acc[n][i] + c4[i];
            Ab[r * 136 + col] = (f16)fmaxf(__expf(v - mx[i]) * sm[i] - thr, 0.f);
          } else if (col < 136) {
            Ab[r * 136 + col] = (f16)0.f;
          }
        }
      }
    }
  }
}

// ---------------- k_gcn: Z = A @ g + b; A-frags direct from global, gT in LDS
template <int FI, int FO, bool RES, bool G1>
__global__ __launch_bounds__(256) void k_gcn(
    const f16* __restrict__ A16, const float* __restrict__ ZP,
    const float* __restrict__ ZQ, const f16* __restrict__ xw1,
    const float* __restrict__ acP, const float* __restrict__ acQ,
    const float* __restrict__ wmat, const float* __restrict__ bb,
    float* __restrict__ Zout, float* __restrict__ sp)
{
  __shared__ f16 gT[16 * 168];                // [n][s], stride 168 (2-way free), zero-pad
  const int b = blockIdx.x, tid = threadIdx.x;
  for (int i = tid; i < 1344; i += 256) ((float*)gT)[i] = 0.f;
  __syncthreads();
  if constexpr (G1) {
    for (int i = tid; i < 2080; i += 256) {
      int s = i >> 4, f = i & 15;
      gT[f * 168 + s] = xw1[(size_t)b * 2080 + i];
    }
  } else {
    if (tid < 130) {
      const int r = tid;
      float h[FI];
      const float* zp = ZP + ((size_t)b * 130 + r) * FI;
      const float aP = acP[r], cP = acP[130 + r];
#pragma unroll
      for (int i = 0; i < FI; i++) h[i] = fmaxf(aP * zp[i] + cP, 0.f);
      if constexpr (RES) {
        const float* zq = ZQ + ((size_t)b * 130 + r) * FI;
        const float aQ = acQ[r], cQ = acQ[130 + r];
#pragma unroll
        for (int i = 0; i < FI; i++) h[i] += fmaxf(aQ * zq[i] + cQ, 0.f);
      }
#pragma unroll
      for (int k = 0; k < FO; k++) {
        float s = 0.f;
#pragma unroll
        for (int i = 0; i < FI; i++) s += h[i] * wmat[k * FI + i];
        gT[k * 168 + r] = (f16)s;             // bias NOT here (added post-A)
      }
    }
  }
  __syncthreads();
  const int lane = tid & 63, wv = tid >> 6, mrow = lane & 15, quad = lane >> 4;
  f16x8 bfr[5];                               // B-frags cached (k = 0..159; >=130 zero)
#pragma unroll
  for (int kk = 0; kk < 5; kk++)
    bfr[kk] = *(const f16x8*)&gT[mrow * 168 + kk * 32 + quad * 8];
  const f16* Ab = A16 + (size_t)b * 17680;
  for (int m = wv; m < 9; m += 4) {
    const f16* arow = Ab + (m * 16 + mrow) * 136 + quad * 8;
    f32x4 acc = (f32x4){0.f, 0.f, 0.f, 0.f};
#pragma unroll
    for (int kk = 0; kk < 5; kk++)            // k>=136 reads next row, B=0 there
      acc = MFMA16(*(const f16x8*)(arow + kk * 32), bfr[kk], acc);
    const int col = mrow;
    const float bk = (col < FO) ? bb[col] : 0.f;
    float p1[4], p2[4];
#pragma unroll
    for (int i = 0; i < 4; i++) {
      int r = m * 16 + quad * 4 + i;
      float v = (col < FO) ? acc[i] + bk : 0.f;
      if (col < FO && r < 130)
        Zout[((size_t)b * 130 + r) * FO + col] = v;
      p1[i] = v; p2[i] = v * v;
    }
#pragma unroll
    for (int i = 0; i < 4; i++)
#pragma unroll
      for (int msk = 1; msk <= 8; msk <<= 1) {
        p1[i] += __shfl_xor(p1[i], msk); p2[i] += __shfl_xor(p2[i], msk);
      }
    if (mrow == 0) {
#pragma unroll
      for (int i = 0; i < 4; i++) {
        int r = m * 16 + quad * 4 + i;
        if (r < 130) {
          sp[(size_t)r * 4096 + b] = p1[i];
          sp[130 * 4096 + (size_t)r * 4096 + b] = p2[i];
        }
      }
    }
  }
}

// ---------------- k_mlp
__global__ __launch_bounds__(256) void k_mlp(
    const float* __restrict__ Z5, const float* __restrict__ Z6,
    const float* __restrict__ ac5, const float* __restrict__ ac6,
    const float* __restrict__ wm, const float* __restrict__ bm, float* __restrict__ out)
{
  const int tid = threadIdx.x, lane = tid & 63, wv = tid >> 6;
  const int b = blockIdx.x * 4 + wv;
  const float* z5 = Z5 + (size_t)b * 260;
  const float* z6 = Z6 + (size_t)b * 260;
  float p0 = 0.f, p1 = 0.f;
#pragma unroll
  for (int j = 0; j < 5; j++) {
    int i = lane + 64 * j;
    if (i < 260) {
      int r = i >> 1;
      float h = fmaxf(ac6[r] * z6[i] + ac6[130 + r], 0.f)
              + fmaxf(ac5[r] * z5[i] + ac5[130 + r], 0.f);
      p0 += h * wm[i];
      p1 += h * wm[260 + i];
    }
  }
#pragma unroll
  for (int m = 1; m <= 32; m <<= 1) { p0 += __shfl_xor(p0, m); p1 += __shfl_xor(p1, m); }
  if (lane == 0) {
    out[(size_t)b * 2] = fmaxf(p0 + bm[0], 0.f);
    out[(size_t)b * 2 + 1] = fmaxf(p1 + bm[1], 0.f);
  }
}

extern "C" void kernel_launch(void* const* d_in, const int* in_sizes, int n_in,
                              void* d_out, int out_size, void* d_ws, size_t ws_size,
                              hipStream_t stream) {
  const float* X   = (const float*)d_in[0];
  const float* THR = (const float*)d_in[1];
  const float* WQ  = (const float*)d_in[2];
  const float* BQ  = (const float*)d_in[3];
  const float* GT  = (const float*)d_in[4];
  const float* BT  = (const float*)d_in[5];
  const float* W1 = (const float*)d_in[6];  const float* Bb1 = (const float*)d_in[7];
  const float* G1g = (const float*)d_in[8]; const float* BE1 = (const float*)d_in[9];
  const float* W2 = (const float*)d_in[10]; const float* Bb2 = (const float*)d_in[11];
  const float* G2 = (const float*)d_in[12]; const float* BE2 = (const float*)d_in[13];
  const float* W3 = (const float*)d_in[14]; const float* Bb3 = (const float*)d_in[15];
  const float* G3 = (const float*)d_in[16]; const float* BE3 = (const float*)d_in[17];
  const float* W4 = (const float*)d_in[18]; const float* Bb4 = (const float*)d_in[19];
  const float* G4 = (const float*)d_in[20]; const float* BE4 = (const float*)d_in[21];
  const float* W5 = (const float*)d_in[22]; const float* Bb5 = (const float*)d_in[23];
  const float* G5 = (const float*)d_in[24]; const float* BE5 = (const float*)d_in[25];
  const float* W6 = (const float*)d_in[26]; const float* Bb6 = (const float*)d_in[27];
  const float* G6 = (const float*)d_in[28]; const float* BE6 = (const float*)d_in[29];
  const float* WM = (const float*)d_in[30]; const float* BM = (const float*)d_in[31];

  float* ws = (float*)d_ws;
  // Workspace (float units). Total ~82.0M floats = 328 MB.
  f16*   A16   = (f16*)ws;                    // 4096*130*136 halfs
  f16*   qk16  = (f16*)(ws + 36208640);       // 532480*64 halfs
  f16*   xw116 = (f16*)(ws + 53248000);       // 532480*16 halfs
  f16*   wf16  = (f16*)(ws + 57507840);       // 80*224 halfs (8960 fl)
  float* Z1 = ws + 57516800;
  float* Z2 = ws + 66036480;
  float* Z3 = ws + 74556160;
  float* Z4 = ws + 76686080;
  float* Z5 = ws + 78816000;
  float* Z6 = ws + 79880960;
  float* sp = ws + 80945920;
  float* ac = ws + 82010880;

  w_prep<<<80, 256, 0, stream>>>(WQ, W1, wf16);
  k_in<<<8320, 256, 0, stream>>>(X, wf16, BQ, qk16, xw116);
  k_relstats<<<4096, 256, 0, stream>>>(qk16, sp);
  k_stats<<<130, 256, 0, stream>>>(sp, GT, BT, 1.f / 532480.f, ac);
  k_Asoft<<<4096, 256, 0, stream>>>(qk16, ac, THR, A16);
  k_gcn<16, 16, false, true><<<4096, 256, 0, stream>>>(A16, nullptr, nullptr, xw116,
      nullptr, nullptr, nullptr, Bb1, Z1, sp);
  k_stats<<<130, 256, 0, stream>>>(sp, G1g, BE1, 1.f / 65536.f, ac + 260);
  k_gcn<16, 16, false, false><<<4096, 256, 0, stream>>>(A16, Z1, nullptr, nullptr,
      ac + 260, nullptr, W2, Bb2, Z2, sp);
  k_stats<<<130, 256, 0, stream>>>(sp, G2, BE2, 1.f / 65536.f, ac + 520);
  k_gcn<16, 4, true, false><<<4096, 256, 0, stream>>>(A16, Z2, Z1, nullptr,
      ac + 520, ac + 260, W3, Bb3, Z3, sp);
  k_stats<<<130, 256, 0, stream>>>(sp, G3, BE3, 1.f / 16384.f, ac + 780);
  k_gcn<4, 4, false, false><<<4096, 256, 0, stream>>>(A16, Z3, nullptr, nullptr,
      ac + 780, nullptr, W4, Bb4, Z4, sp);
  k_stats<<<130, 256, 0, stream>>>(sp, G4, BE4, 1.f / 16384.f, ac + 1040);
  k_gcn<4, 2, true, false><<<4096, 256, 0, stream>>>(A16, Z4, Z3, nullptr,
      ac + 1040, ac + 780, W5, Bb5, Z5, sp);
  k_stats<<<130, 256, 0, stream>>>(sp, G5, BE5, 1.f / 8192.f, ac + 1300);
  k_gcn<2, 2, false, false><<<4096, 256, 0, stream>>>(A16, Z5, nullptr, nullptr,
      ac + 1300, nullptr, W6, Bb6, Z6, sp);
  k_stats<<<130, 256, 0, stream>>>(sp, G6, BE6, 1.f / 8192.f, ac + 1560);
  k_mlp<<<1024, 256, 0, stream>>>(Z5, Z6, ac + 1300, ac + 1560, WM, BM, (float*)d_out);
}